// Round 5
// baseline (101.182 us; speedup 1.0000x reference)
//
#include <hip/hip_runtime.h>
#include <hip/hip_bf16.h>

#define S_DIM 1024
#define B_DIM 64
#define A_DIM 1024

// K2 = 2*log2(e): tanh(x) = 1 - 2/(exp2(K2*x)+1)
#define K2_CONST 2.8853900817779268f

#define K_TILE 64
#define KSPLIT 16
#define A_TILE 64
#define SSPLIT 16
#define S_CHUNK 64

typedef float f4 __attribute__((ext_vector_type(4)));

__device__ __forceinline__ float fast_exp2(float x) { return __builtin_amdgcn_exp2f(x); }
__device__ __forceinline__ float fast_rcp(float x)  { return __builtin_amdgcn_rcpf(x); }

// ---------------------------------------------------------------------------
// Kernel 1: split-K GEMM partials   part[kz][b][a] = sum_{k in chunk} s_tm1[b,k]*sa_w[a,k]
// ---------------------------------------------------------------------------
__global__ __launch_bounds__(256) void gemm_partial_kernel(
    const float* __restrict__ s_tm1,   // [B][1024]
    const float* __restrict__ sa_w,    // [1024][1024]
    float* __restrict__ part)          // [KSPLIT][B][1024]
{
    __shared__ float sW[K_TILE][68];   // [k][a_local]
    __shared__ float sS[K_TILE][68];   // [k][b]
    const int a0 = blockIdx.x * A_TILE;
    const int k0 = blockIdx.y * K_TILE;
    const int t  = threadIdx.x;

    #pragma unroll
    for (int i = 0; i < 4; ++i) {
        int idx = t + 256 * i;
        int row = idx >> 4;
        int c4  = (idx & 15) * 4;
        f4 v = __builtin_nontemporal_load((const f4*)(sa_w + (size_t)(a0 + row) * 1024 + k0 + c4));
        sW[c4 + 0][row] = v.x; sW[c4 + 1][row] = v.y;
        sW[c4 + 2][row] = v.z; sW[c4 + 3][row] = v.w;
        f4 u = *(const f4*)(s_tm1 + (size_t)row * 1024 + k0 + c4);
        sS[c4 + 0][row] = u.x; sS[c4 + 1][row] = u.y;
        sS[c4 + 2][row] = u.z; sS[c4 + 3][row] = u.w;
    }
    __syncthreads();

    const int ta = (t & 15) * 4;       // a_local base
    const int tb = (t >> 4) * 4;       // b base
    float acc[4][4] = {};
    #pragma unroll 8
    for (int k = 0; k < K_TILE; ++k) {
        f4 wa = *(const f4*)&sW[k][ta];
        f4 sb = *(const f4*)&sS[k][tb];
        float wv[4] = {wa.x, wa.y, wa.z, wa.w};
        float sv[4] = {sb.x, sb.y, sb.z, sb.w};
        #pragma unroll
        for (int i = 0; i < 4; ++i)
            #pragma unroll
            for (int j = 0; j < 4; ++j)
                acc[i][j] = fmaf(wv[i], sv[j], acc[i][j]);
    }

    float* outp = part + (size_t)blockIdx.y * (B_DIM * 1024);
    #pragma unroll
    for (int j = 0; j < 4; ++j) {
        f4 v = {acc[0][j], acc[1][j], acc[2][j], acc[3][j]};
        *(f4*)(outp + (size_t)(tb + j) * 1024 + a0 + ta) = v;
    }
}

// ---------------------------------------------------------------------------
// Kernel 1b: ksa[b][a] = K2 * (sa_b[a] + sum_kz part[kz][b][a])
// ---------------------------------------------------------------------------
__global__ __launch_bounds__(256) void gemm_reduce_kernel(
    const float* __restrict__ part, const float* __restrict__ sa_b,
    float* __restrict__ ksa)           // [B][1024]
{
    int idx = blockIdx.x * 256 + threadIdx.x;   // over [B][1024]
    int a = idx & 1023;
    float s = sa_b[a];
    #pragma unroll
    for (int kz = 0; kz < KSPLIT; ++kz)
        s += part[(size_t)kz * 65536 + idx];
    ksa[idx] = K2_CONST * s;
}

// ---------------------------------------------------------------------------
// Kernel 2 (fused, explicit 2-deep pipeline): per (b, s-chunk) block, wave w
// handles rows {w, w+4, ..., w+60}. Row k+1's uh fragment is issued BEFORE
// row k's compute so ~4 KB/wave stays in flight under the exp/reduce chain.
// ---------------------------------------------------------------------------
__global__ __launch_bounds__(256) void fused_kernel(
    const float* __restrict__ uh,      // [S][B][1024]
    const float* __restrict__ xs_h,    // [S][B][1024]
    const float* __restrict__ ksa,     // [B][1024] (pre-scaled by K2)
    const float* __restrict__ a1_w,    // [1024]
    const float* __restrict__ xs_mask, // [S][B]
    float* __restrict__ ex_buf,        // [S][B] (unnormalized masked ex)
    float* __restrict__ psum,          // [SSPLIT][B]
    float* __restrict__ part)          // [SSPLIT][B][1024]
{
    const int b    = blockIdx.x;
    const int sz   = blockIdx.y;
    const int s0   = sz * S_CHUNK;
    const int t    = threadIdx.x;
    const int lane = t & 63;
    const int w    = t >> 6;

    __shared__ float s_ex[S_CHUNK];
    __shared__ float s_mask[S_CHUNK];
    __shared__ f4 s_red[4][256];

    if (t < S_CHUNK) s_mask[t] = xs_mask[(size_t)(s0 + t) * B_DIM + b];

    // block-invariant fragments -> registers
    const f4* sap = (const f4*)(ksa + (size_t)b * 1024);
    const f4* awp = (const f4*)a1_w;
    f4 sv[4], aw[4];
    #pragma unroll
    for (int j = 0; j < 4; ++j) { sv[j] = sap[lane + 64 * j]; aw[j] = awp[lane + 64 * j]; }

    __syncthreads();

    f4 acc4[4];
    #pragma unroll
    for (int j = 0; j < 4; ++j) { acc4[j].x = 0.f; acc4[j].y = 0.f; acc4[j].z = 0.f; acc4[j].w = 0.f; }

    // base row offset for this wave: row(k) = s0 + w + 4k
    size_t rowoff = ((size_t)(s0 + w) * B_DIM + b) * 1024;
    const size_t rowstep = (size_t)4 * B_DIM * 1024;   // 4 rows ahead

    f4 ucur[4], unxt[4], xv[4];

    // prologue: issue row 0's uh
    {
        const f4* up = (const f4*)(uh + rowoff);
        #pragma unroll
        for (int j = 0; j < 4; ++j) ucur[j] = __builtin_nontemporal_load(&up[lane + 64 * j]);
    }

    #pragma unroll 1
    for (int k = 0; k < 16; ++k) {
        const int i = w + 4 * k;

        // 1) prefetch next row's uh (stays in flight through this row's compute)
        if (k < 15) {
            const f4* un = (const f4*)(uh + rowoff + rowstep);
            #pragma unroll
            for (int j = 0; j < 4; ++j) unxt[j] = __builtin_nontemporal_load(&un[lane + 64 * j]);
        }
        // 2) issue this row's xs_h (L3-resident; needed only after the reduce)
        {
            const f4* xp = (const f4*)(xs_h + rowoff);
            #pragma unroll
            for (int j = 0; j < 4; ++j) xv[j] = xp[lane + 64 * j];
        }

        // 3) exp/rcp chain on ucur (waits only for ucur: vmcnt(8))
        float acc = 0.f;
        #pragma unroll
        for (int j = 0; j < 4; ++j) {
            float t0 = fast_exp2(fmaf(K2_CONST, ucur[j].x, sv[j].x));
            float t1 = fast_exp2(fmaf(K2_CONST, ucur[j].y, sv[j].y));
            float t2 = fast_exp2(fmaf(K2_CONST, ucur[j].z, sv[j].z));
            float t3 = fast_exp2(fmaf(K2_CONST, ucur[j].w, sv[j].w));
            acc = fmaf(aw[j].x, fast_rcp(1.0f + t0), acc);
            acc = fmaf(aw[j].y, fast_rcp(1.0f + t1), acc);
            acc = fmaf(aw[j].z, fast_rcp(1.0f + t2), acc);
            acc = fmaf(aw[j].w, fast_rcp(1.0f + t3), acc);
        }
        #pragma unroll
        for (int off = 32; off; off >>= 1) acc += __shfl_xor(acc, off);

        float ex = fast_exp2(-K2_CONST * acc) * s_mask[i];
        if (lane == 0) s_ex[i] = ex;

        // 4) accumulate this row's xs_h
        #pragma unroll
        for (int j = 0; j < 4; ++j) {
            acc4[j].x = fmaf(ex, xv[j].x, acc4[j].x);
            acc4[j].y = fmaf(ex, xv[j].y, acc4[j].y);
            acc4[j].z = fmaf(ex, xv[j].z, acc4[j].z);
            acc4[j].w = fmaf(ex, xv[j].w, acc4[j].w);
        }

        // 5) rotate pipeline
        #pragma unroll
        for (int j = 0; j < 4; ++j) ucur[j] = unxt[j];
        rowoff += rowstep;
    }

    // combine 4 waves' partials
    #pragma unroll
    for (int j = 0; j < 4; ++j) s_red[w][lane + 64 * j] = acc4[j];
    __syncthreads();

    f4 r = s_red[0][t];
    #pragma unroll
    for (int ww = 1; ww < 4; ++ww) {
        f4 q = s_red[ww][t];
        r.x += q.x; r.y += q.y; r.z += q.z; r.w += q.w;
    }
    ((f4*)part)[((size_t)sz * B_DIM + b) * 256 + t] = r;

    if (t < S_CHUNK)
        ex_buf[(size_t)(s0 + t) * B_DIM + b] = s_ex[t];

    if (w == 0) {
        float v = s_ex[lane];
        #pragma unroll
        for (int off = 32; off; off >>= 1) v += __shfl_xor(v, off);
        if (lane == 0) psum[sz * B_DIM + b] = v;
    }
}

// ---------------------------------------------------------------------------
// Kernel 3 (finalize): blocks 0..255: eij = ex_buf * inv_sum[b]
//                      blocks 256..511: attend = (sum_sz part) * inv_sum[b]
// ---------------------------------------------------------------------------
__global__ __launch_bounds__(256) void finalize_kernel(
    const float* __restrict__ ex_buf, const float* __restrict__ part,
    const float* __restrict__ psum,
    float* __restrict__ eij_out, float* __restrict__ att_out)
{
    const int blk = blockIdx.x;
    const int t = threadIdx.x;
    if (blk < 256) {
        int idx = blk * 256 + t;           // over [S][B]
        int b = idx & 63;
        float ssum = 0.f;
        #pragma unroll
        for (int sz = 0; sz < SSPLIT; ++sz) ssum += psum[sz * B_DIM + b];
        eij_out[idx] = ex_buf[idx] * (1.0f / ssum);
    } else {
        int idx = (blk - 256) * 256 + t;   // over [B][1024]
        int b = idx >> 10;
        float ssum = 0.f;
        #pragma unroll
        for (int sz = 0; sz < SSPLIT; ++sz) ssum += psum[sz * B_DIM + b];
        float acc = 0.f;
        #pragma unroll
        for (int sz = 0; sz < SSPLIT; ++sz) acc += part[(size_t)sz * 65536 + idx];
        att_out[idx] = acc * (1.0f / ssum);
    }
}

// ---------------------------------------------------------------------------
extern "C" void kernel_launch(void* const* d_in, const int* in_sizes, int n_in,
                              void* d_out, int out_size, void* d_ws, size_t ws_size,
                              hipStream_t stream) {
    const float* s_tm1   = (const float*)d_in[0];  // [64][1024]
    const float* xs_h    = (const float*)d_in[1];  // [1024][64][1024]
    const float* uh      = (const float*)d_in[2];  // [1024][64][1024]
    const float* xs_mask = (const float*)d_in[3];  // [1024][64]
    const float* sa_w    = (const float*)d_in[4];  // [1024][1024]
    const float* sa_b    = (const float*)d_in[5];  // [1024]
    const float* a1_w    = (const float*)d_in[6];  // [1][1024]
    // d_in[7] = a1_b: global constant shift -> cancels in softmax.

    float* eij_out = (float*)d_out;                 // [S][B]
    float* att_out = (float*)d_out + S_DIM * B_DIM; // [B][1024]

    float* part_gemm = (float*)d_ws;                               // 16*64*1024
    float* ksa       = part_gemm + (size_t)KSPLIT * B_DIM * 1024;  // 64*1024
    float* ex_buf    = ksa + 65536;                                // [S][B]
    float* part_att  = ex_buf + 65536;                             // 16*64*1024
    float* psum      = part_att + (size_t)SSPLIT * B_DIM * 1024;   // 16*64

    gemm_partial_kernel<<<dim3(A_DIM / A_TILE, KSPLIT), 256, 0, stream>>>(s_tm1, sa_w, part_gemm);
    gemm_reduce_kernel<<<65536 / 256, 256, 0, stream>>>(part_gemm, sa_b, ksa);
    fused_kernel<<<dim3(B_DIM, SSPLIT), 256, 0, stream>>>(uh, xs_h, ksa, a1_w, xs_mask,
                                                          ex_buf, psum, part_att);
    finalize_kernel<<<512, 256, 0, stream>>>(ex_buf, part_att, psum, eij_out, att_out);
}